// Round 1
// baseline (206.120 us; speedup 1.0000x reference)
//
#include <hip/hip_runtime.h>
#include <hip/hip_bf16.h>
#include <stdint.h>

typedef short bf16x8 __attribute__((ext_vector_type(8)));   // 8 bf16 in 4 VGPRs
typedef float f32x4 __attribute__((ext_vector_type(4)));
typedef unsigned short u16;
typedef u16 ushort8 __attribute__((ext_vector_type(8)));

typedef __attribute__((address_space(3))) void lds_void;
typedef const __attribute__((address_space(1))) void gbl_void;

__device__ __forceinline__ u16 f2bf(float f) {
  uint32_t u = __builtin_bit_cast(uint32_t, f);
  u += 0x7fffu + ((u >> 16) & 1u);   // round-to-nearest-even
  return (u16)(u >> 16);
}

// ---------------- x: f32 -> bf16 ----------------
__global__ __launch_bounds__(256) void cvt_x(const float* __restrict__ x,
                                             u16* __restrict__ xb) {
  const int i = (blockIdx.x * 256 + threadIdx.x) * 8;
  float4 a = *(const float4*)(x + i);
  float4 b = *(const float4*)(x + i + 4);
  ushort8 o;
  o[0] = f2bf(a.x); o[1] = f2bf(a.y); o[2] = f2bf(a.z); o[3] = f2bf(a.w);
  o[4] = f2bf(b.x); o[5] = f2bf(b.y); o[6] = f2bf(b.z); o[7] = f2bf(b.w);
  *(ushort8*)(xb + i) = o;
}

// ---------------- build Mt[j][i] = M[i][j] (bf16, 4096x4096) ----------------
// M[i,j] = sum_{r1,r2,r3} G0[0,i0,j0,r1] G1[r1,i1,j1,r2] G2[r2,i2,j2,r3] G3[r3,i3,j3,0]
// i = i0*512+i1*64+i2*8+i3 (big-endian), j likewise.
// One block per (i0,j0,i1,j1); block computes the 64x64 tile Mt[j0j1*, i0i1*].
__global__ __launch_bounds__(256) void build_mt(
    const float* __restrict__ c0, const float* __restrict__ c1,
    const float* __restrict__ c2, const float* __restrict__ c3,
    u16* __restrict__ Mt) {
  const int bid = blockIdx.x;
  const int j1 = bid & 7, i1 = (bid >> 3) & 7, j0 = (bid >> 6) & 7, i0 = bid >> 9;
  const int t = threadIdx.x;
  __shared__ float v[512];   // [i2][j2][r3]
  __shared__ float g3[512];  // copy of c3 [r3][i3][j3]
  g3[t] = c3[t];
  g3[t + 256] = c3[t + 256];
  // w2[r2] = sum_r1 G0[i0,j0,r1] * G1[r1,i1,j1,r2]  (uniform per block)
  float w2[8];
#pragma unroll
  for (int r2 = 0; r2 < 8; ++r2) {
    float s = 0.f;
#pragma unroll
    for (int r1 = 0; r1 < 8; ++r1)
      s += c0[(i0 * 8 + j0) * 8 + r1] * c1[((r1 * 8 + i1) * 8 + j1) * 8 + r2];
    w2[r2] = s;
  }
#pragma unroll
  for (int e = t; e < 512; e += 256) {
    const int r3 = e & 7, j2 = (e >> 3) & 7, i2 = e >> 6;
    float s = 0.f;
#pragma unroll
    for (int r2 = 0; r2 < 8; ++r2)
      s += w2[r2] * c2[((r2 * 8 + i2) * 8 + j2) * 8 + r3];
    v[e] = s;
  }
  __syncthreads();
  // outputs: row jr = j2*8+j3 (0..63), col ic = i2*8+i3 (0..63)
  const int jr = t >> 2, ic0 = (t & 3) * 16;
  const int j2 = jr >> 3, j3 = jr & 7;
  const size_t base =
      (size_t)(j0 * 512 + j1 * 64 + jr) * 4096 + (i0 * 512 + i1 * 64) + ic0;
  ushort8 o0, o1;
#pragma unroll
  for (int q = 0; q < 16; ++q) {
    const int ic = ic0 + q, i2 = ic >> 3, i3 = ic & 7;
    float s = 0.f;
#pragma unroll
    for (int r3 = 0; r3 < 8; ++r3)
      s += v[(i2 << 6) + (j2 << 3) + r3] * g3[(r3 << 6) + (i3 << 3) + j3];
    const u16 h = f2bf(s);
    if (q < 8) o0[q] = h; else o1[q - 8] = h;
  }
  *(ushort8*)(Mt + base) = o0;
  *(ushort8*)(Mt + base + 8) = o1;
}

// ---------------- GEMM: C = relu(A(bf16) * Bt^T(bf16) + bias), fp32 out ----
// A: [4096][4096] bf16 row-major (M x K); Bt: [4096][4096] bf16 (N x K).
// 128x128 tile, BK=32, 4 waves 2x2, each wave 64x64 = 4x4 frags of 16x16x32.
// LDS tiles [128 rows][64B] with chunk-XOR swizzle: chunk ^= (row>>1)&3,
// applied on the pre-swizzled global source AND on the ds_read address.
__global__ __launch_bounds__(256) void gemm_bias_relu(
    const u16* __restrict__ A, const u16* __restrict__ Bt,
    const float* __restrict__ bias, float* __restrict__ C) {
  constexpr int K = 4096, N = 4096;
  __shared__ __align__(16) char lds[2][16384];  // per buf: A 8KB, B 8KB
  const int t = threadIdx.x;
  const int l = t & 63, w = t >> 6;
  const int wr = w >> 1, wc = w & 1;
  const int lr = l & 15, lk = l >> 4;
  const int bm = blockIdx.y, bn = blockIdx.x;

  // staging: per inst s, thread t fills LDS bytes [s*4096 + t*16, +16)
  const int srow = t >> 2;                       // + s*64
  const int schunk = (t & 3) ^ ((t >> 3) & 3);   // pre-swizzled source chunk
  const char* gA = (const char*)(A + (size_t)bm * 128 * K);
  const char* gB = (const char*)(Bt + (size_t)bn * 128 * K);

  // fragment ds_read byte offsets (swizzled), constant across K-loop
  const int sw = (lr >> 1) & 3;
  const int cOff = (lk ^ sw) << 4;
  int aoff[4], boff[4];
#pragma unroll
  for (int m = 0; m < 4; ++m) aoff[m] = (wr * 64 + m * 16 + lr) * 64 + cOff;
#pragma unroll
  for (int n = 0; n < 4; ++n) boff[n] = 8192 + (wc * 64 + n * 16 + lr) * 64 + cOff;

  f32x4 acc[4][4];
#pragma unroll
  for (int m = 0; m < 4; ++m)
#pragma unroll
    for (int n = 0; n < 4; ++n) acc[m][n] = f32x4{0.f, 0.f, 0.f, 0.f};

  auto stage = [&](int buf, int kt) {
    const int kb = kt * 64;
#pragma unroll
    for (int s = 0; s < 2; ++s) {
      const size_t go = (size_t)(s * 64 + srow) * (K * 2) + kb + schunk * 16;
      __builtin_amdgcn_global_load_lds((gbl_void*)(gA + go),
                                       (lds_void*)(&lds[buf][s * 4096 + w * 1024]),
                                       16, 0, 0);
      __builtin_amdgcn_global_load_lds((gbl_void*)(gB + go),
                                       (lds_void*)(&lds[buf][8192 + s * 4096 + w * 1024]),
                                       16, 0, 0);
    }
  };

  stage(0, 0);
  __syncthreads();
  int cur = 0;
  for (int kt = 0; kt < K / 32; ++kt) {
    if (kt + 1 < K / 32) stage(cur ^ 1, kt + 1);
    const char* Lb = lds[cur];
    bf16x8 af[4], bfr[4];
#pragma unroll
    for (int m = 0; m < 4; ++m) af[m] = *(const bf16x8*)(Lb + aoff[m]);
#pragma unroll
    for (int n = 0; n < 4; ++n) bfr[n] = *(const bf16x8*)(Lb + boff[n]);
#pragma unroll
    for (int m = 0; m < 4; ++m)
#pragma unroll
      for (int n = 0; n < 4; ++n)
        acc[m][n] = __builtin_amdgcn_mfma_f32_16x16x32_bf16(af[m], bfr[n],
                                                            acc[m][n], 0, 0, 0);
    __syncthreads();
    cur ^= 1;
  }

  // epilogue: D lane mapping col = l&15, row = (l>>4)*4 + v
  const int row0 = bm * 128 + wr * 64;
  const int col0 = bn * 128 + wc * 64;
#pragma unroll
  for (int n = 0; n < 4; ++n) {
    const int col = col0 + n * 16 + lr;
    const float bv = bias[col];
#pragma unroll
    for (int m = 0; m < 4; ++m) {
      const int r0 = row0 + m * 16 + lk * 4;
#pragma unroll
      for (int vv = 0; vv < 4; ++vv) {
        const float val = acc[m][n][vv] + bv;
        C[(size_t)(r0 + vv) * N + col] = val > 0.f ? val : 0.f;
      }
    }
  }
}

extern "C" void kernel_launch(void* const* d_in, const int* in_sizes, int n_in,
                              void* d_out, int out_size, void* d_ws, size_t ws_size,
                              hipStream_t stream) {
  const float* x  = (const float*)d_in[0];
  const float* c0 = (const float*)d_in[1];
  const float* c1 = (const float*)d_in[2];
  const float* c2 = (const float*)d_in[3];
  const float* c3 = (const float*)d_in[4];
  const float* b  = (const float*)d_in[5];
  float* out = (float*)d_out;

  u16* xb  = (u16*)d_ws;                       // 32 MB bf16 x
  u16* mtb = xb + (size_t)4096 * 4096;         // 32 MB bf16 M^T

  cvt_x<<<dim3(16777216 / (256 * 8)), dim3(256), 0, stream>>>(x, xb);
  build_mt<<<dim3(4096), dim3(256), 0, stream>>>(c0, c1, c2, c3, mtb);
  gemm_bias_relu<<<dim3(32, 32), dim3(256), 0, stream>>>(xb, mtb, b, out);
}

// Round 2
// 145.310 us; speedup vs baseline: 1.4185x; 1.4185x over previous
//
#include <hip/hip_runtime.h>
#include <hip/hip_bf16.h>
#include <stdint.h>

typedef short bf16x8 __attribute__((ext_vector_type(8)));   // 8 bf16 in 4 VGPRs
typedef float f32x4 __attribute__((ext_vector_type(4)));
typedef unsigned short u16;
typedef u16 ushort8 __attribute__((ext_vector_type(8)));

typedef __attribute__((address_space(3))) void lds_void;
typedef const __attribute__((address_space(1))) void gbl_void;

#define BAR() do { asm volatile("" ::: "memory"); __builtin_amdgcn_s_barrier(); asm volatile("" ::: "memory"); } while (0)
#define WAITV(N) asm volatile("s_waitcnt vmcnt(" #N ")" ::: "memory")
#define WAITL0() do { asm volatile("s_waitcnt lgkmcnt(0)" ::: "memory"); __builtin_amdgcn_sched_barrier(0); } while (0)
#define SCHED() __builtin_amdgcn_sched_barrier(0)

__device__ __forceinline__ u16 f2bf(float f) {
  uint32_t u = __builtin_bit_cast(uint32_t, f);
  u += 0x7fffu + ((u >> 16) & 1u);   // round-to-nearest-even
  return (u16)(u >> 16);
}

// ---------------- x: f32 -> bf16 ----------------
__global__ __launch_bounds__(256) void cvt_x(const float* __restrict__ x,
                                             u16* __restrict__ xb) {
  const int i = (blockIdx.x * 256 + threadIdx.x) * 8;
  float4 a = *(const float4*)(x + i);
  float4 b = *(const float4*)(x + i + 4);
  ushort8 o;
  o[0] = f2bf(a.x); o[1] = f2bf(a.y); o[2] = f2bf(a.z); o[3] = f2bf(a.w);
  o[4] = f2bf(b.x); o[5] = f2bf(b.y); o[6] = f2bf(b.z); o[7] = f2bf(b.w);
  *(ushort8*)(xb + i) = o;
}

// ---------------- build Mt[j][i] = M[i][j] (bf16, 4096x4096) ----------------
__global__ __launch_bounds__(256) void build_mt(
    const float* __restrict__ c0, const float* __restrict__ c1,
    const float* __restrict__ c2, const float* __restrict__ c3,
    u16* __restrict__ Mt) {
  const int bid = blockIdx.x;
  const int j1 = bid & 7, i1 = (bid >> 3) & 7, j0 = (bid >> 6) & 7, i0 = bid >> 9;
  const int t = threadIdx.x;
  __shared__ float v[512];   // [i2][j2][r3]
  __shared__ float g3[512];  // copy of c3 [r3][i3][j3]
  g3[t] = c3[t];
  g3[t + 256] = c3[t + 256];
  float w2[8];
#pragma unroll
  for (int r2 = 0; r2 < 8; ++r2) {
    float s = 0.f;
#pragma unroll
    for (int r1 = 0; r1 < 8; ++r1)
      s += c0[(i0 * 8 + j0) * 8 + r1] * c1[((r1 * 8 + i1) * 8 + j1) * 8 + r2];
    w2[r2] = s;
  }
#pragma unroll
  for (int e = t; e < 512; e += 256) {
    const int r3 = e & 7, j2 = (e >> 3) & 7, i2 = e >> 6;
    float s = 0.f;
#pragma unroll
    for (int r2 = 0; r2 < 8; ++r2)
      s += w2[r2] * c2[((r2 * 8 + i2) * 8 + j2) * 8 + r3];
    v[e] = s;
  }
  __syncthreads();
  const int jr = t >> 2, ic0 = (t & 3) * 16;
  const int j2 = jr >> 3, j3 = jr & 7;
  const size_t base =
      (size_t)(j0 * 512 + j1 * 64 + jr) * 4096 + (i0 * 512 + i1 * 64) + ic0;
  ushort8 o0, o1;
#pragma unroll
  for (int q = 0; q < 16; ++q) {
    const int ic = ic0 + q, i2 = ic >> 3, i3 = ic & 7;
    float s = 0.f;
#pragma unroll
    for (int r3 = 0; r3 < 8; ++r3)
      s += v[(i2 << 6) + (j2 << 3) + r3] * g3[(r3 << 6) + (i3 << 3) + j3];
    const u16 h = f2bf(s);
    if (q < 8) o0[q] = h; else o1[q - 8] = h;
  }
  *(ushort8*)(Mt + base) = o0;
  *(ushort8*)(Mt + base + 8) = o1;
}

// ---------------- GEMM: 256x256 tile, BK=64, 8-phase counted-vmcnt schedule --
// A: [4096][4096] bf16 (M x K); Bt: [4096][4096] bf16 (N x K).
// 8 waves (2Mx4N), per-wave 128x64 out = 8m x 4n frags of 16x16x32.
// LDS 128KB: A bufs [0,32K),[32K,64K); B bufs [64K,96K),[96K,128K).
// Row = 128B = 8 chunks of 16B, chunk stored at (c ^ (row&7)) -- swizzle applied
// on pre-swizzled global source (staging) and on ds_read address (rule #21).
// Phase program per K-tile t (buf p = t&1):
//   P1: vmcnt(12); rd A(t)kk1 x8;                     MFMA m*,nh0,kk0
//   P2: vmcnt(8);  rd B(t)nh1 x4;  stage Ah0(t+2)->p; MFMA m*,nh0,kk1
//   P3: vmcnt(2);  rd B(t+1)nh0 x4;stage Ah1,Bh0(t+2)->p; MFMA m*,nh1,kk0
//   P4: vmcnt(10); rd A(t+1)kk0 x8;stage Bh1(t+2)->p; MFMA m*,nh1,kk1
// Every staged region's last ds_read completed before the stage issues
// (separated by a full barrier), so gload_lds writes cannot race reads.
__global__ __launch_bounds__(512, 2) void gemm_bias_relu(
    const u16* __restrict__ A, const u16* __restrict__ Bt,
    const float* __restrict__ bias, float* __restrict__ C) {
  constexpr int K = 4096, N = 4096, NT = 64;
  __shared__ __align__(16) char lds[131072];
  const int t = threadIdx.x;
  const int l = t & 63, w = t >> 6;
  const int wr = w >> 2, wc = w & 3;            // 2 x 4 wave grid
  const int lr = l & 15, lk = l >> 4;
  const int bm = blockIdx.y, bn = blockIdx.x;

  const char* gA = (const char*)A + (size_t)bm * 256 * (K * 2);
  const char* gB = (const char*)Bt + (size_t)bn * 256 * (K * 2);
  const int srow = t >> 3;                      // 0..63
  const int schunk = (t & 7) ^ (srow & 7);      // pre-swizzled source chunk
  const int sgo = srow * (K * 2) + schunk * 16;
  const int sld = t * 16;

  // ds_read per-lane byte offsets (swizzled)
  const int axor = (lk ^ (lr & 7)) * 16;        // kk0 chunk; kk1 = axor ^ 64
  const int aoff0 = (wr * 128 + lr) * 128 + axor;
  const int aoff1 = aoff0 ^ 64;
  const int boff0 = 65536 + (wc * 64 + lr) * 128 + axor;
  const int boff1 = boff0 ^ 64;

  auto stA = [&](int p, int h, int kt) {
    const char* src = gA + (size_t)(h * 128) * (K * 2) + kt * 128 + sgo;
    char* dst = lds + p * 32768 + h * 16384 + sld;
    __builtin_amdgcn_global_load_lds((gbl_void*)src, (lds_void*)dst, 16, 0, 0);
    __builtin_amdgcn_global_load_lds((gbl_void*)(src + (size_t)64 * (K * 2)),
                                     (lds_void*)(dst + 8192), 16, 0, 0);
  };
  auto stB = [&](int p, int h, int kt) {
    const char* src = gB + (size_t)(h * 128) * (K * 2) + kt * 128 + sgo;
    char* dst = lds + 65536 + p * 32768 + h * 16384 + sld;
    __builtin_amdgcn_global_load_lds((gbl_void*)src, (lds_void*)dst, 16, 0, 0);
    __builtin_amdgcn_global_load_lds((gbl_void*)(src + (size_t)64 * (K * 2)),
                                     (lds_void*)(dst + 8192), 16, 0, 0);
  };
  auto rdA = [&](int p, int off, int m) -> bf16x8 {
    return *(const bf16x8*)(lds + p * 32768 + off + m * 2048);
  };
  auto rdB = [&](int p, int off, int n) -> bf16x8 {
    return *(const bf16x8*)(lds + p * 32768 + off + n * 2048);
  };

  bf16x8 a0[8], a1[8], b0[2][2], b1[2][2];
  f32x4 acc[8][4];
#pragma unroll
  for (int m = 0; m < 8; ++m)
#pragma unroll
    for (int n = 0; n < 4; ++n) acc[m][n] = f32x4{0.f, 0.f, 0.f, 0.f};

  // ---- prologue: stage K-tiles 0 and 1, land tile 0, preload its regs ----
  stA(0, 0, 0); stA(0, 1, 0); stB(0, 0, 0); stB(0, 1, 0);
  stA(1, 0, 1); stA(1, 1, 1); stB(1, 0, 1); stB(1, 1, 1);
  WAITV(8);
  BAR();
#pragma unroll
  for (int m = 0; m < 8; ++m) a0[m] = rdA(0, aoff0, m);
#pragma unroll
  for (int n = 0; n < 2; ++n) { b0[n][0] = rdB(0, boff0, n); b0[n][1] = rdB(0, boff1, n); }

  // ---- main loop: 2 K-tiles (8 phases) per iteration ----
  for (int it = 0; it < NT / 2; ++it) {
#pragma unroll
    for (int hf = 0; hf < 2; ++hf) {
      const int p = hf;
      const int kt = 2 * it + hf;
      const int kn = (kt + 2) & (NT - 1);       // clamped prefetch tile
      // ---------- P1 ----------
      WAITV(12);
#pragma unroll
      for (int m = 0; m < 8; ++m) a1[m] = rdA(p, aoff1, m);
      BAR(); WAITL0();
      __builtin_amdgcn_s_setprio(1);
#pragma unroll
      for (int m = 0; m < 8; ++m)
#pragma unroll
        for (int n = 0; n < 2; ++n)
          acc[m][n] = __builtin_amdgcn_mfma_f32_16x16x32_bf16(a0[m], b0[n][0], acc[m][n], 0, 0, 0);
      __builtin_amdgcn_s_setprio(0); SCHED();
      BAR();
      // ---------- P2 ----------
      WAITV(8);
#pragma unroll
      for (int n = 0; n < 2; ++n) { b1[n][0] = rdB(p, boff0, n + 2); b1[n][1] = rdB(p, boff1, n + 2); }
      stA(p, 0, kn);
      BAR(); WAITL0();
      __builtin_amdgcn_s_setprio(1);
#pragma unroll
      for (int m = 0; m < 8; ++m)
#pragma unroll
        for (int n = 0; n < 2; ++n)
          acc[m][n] = __builtin_amdgcn_mfma_f32_16x16x32_bf16(a1[m], b0[n][1], acc[m][n], 0, 0, 0);
      __builtin_amdgcn_s_setprio(0); SCHED();
      BAR();
      // ---------- P3 ----------
      WAITV(2);
#pragma unroll
      for (int n = 0; n < 2; ++n) { b0[n][0] = rdB(p ^ 1, boff0, n); b0[n][1] = rdB(p ^ 1, boff1, n); }
      stA(p, 1, kn); stB(p, 0, kn);
      BAR(); WAITL0();
      __builtin_amdgcn_s_setprio(1);
#pragma unroll
      for (int m = 0; m < 8; ++m)
#pragma unroll
        for (int n = 0; n < 2; ++n)
          acc[m][2 + n] = __builtin_amdgcn_mfma_f32_16x16x32_bf16(a0[m], b1[n][0], acc[m][2 + n], 0, 0, 0);
      __builtin_amdgcn_s_setprio(0); SCHED();
      BAR();
      // ---------- P4 ----------
      WAITV(10);
#pragma unroll
      for (int m = 0; m < 8; ++m) a0[m] = rdA(p ^ 1, aoff0, m);
      stB(p, 1, kn);
      BAR(); WAITL0();
      __builtin_amdgcn_s_setprio(1);
#pragma unroll
      for (int m = 0; m < 8; ++m)
#pragma unroll
        for (int n = 0; n < 2; ++n)
          acc[m][2 + n] = __builtin_amdgcn_mfma_f32_16x16x32_bf16(a1[m], b1[n][1], acc[m][2 + n], 0, 0, 0);
      __builtin_amdgcn_s_setprio(0); SCHED();
      BAR();
    }
  }

  // ---- epilogue: bias + relu, fp32 stores ----
  const int row0 = bm * 256 + wr * 128;
  const int col0 = bn * 256 + wc * 64;
#pragma unroll
  for (int n = 0; n < 4; ++n) {
    const int col = col0 + n * 16 + lr;
    const float bv = bias[col];
#pragma unroll
    for (int m = 0; m < 8; ++m) {
      const int r0 = row0 + m * 16 + lk * 4;
#pragma unroll
      for (int vv = 0; vv < 4; ++vv) {
        const float val = acc[m][n][vv] + bv;
        C[(size_t)(r0 + vv) * N + col] = val > 0.f ? val : 0.f;
      }
    }
  }
}

extern "C" void kernel_launch(void* const* d_in, const int* in_sizes, int n_in,
                              void* d_out, int out_size, void* d_ws, size_t ws_size,
                              hipStream_t stream) {
  const float* x  = (const float*)d_in[0];
  const float* c0 = (const float*)d_in[1];
  const float* c1 = (const float*)d_in[2];
  const float* c2 = (const float*)d_in[3];
  const float* c3 = (const float*)d_in[4];
  const float* b  = (const float*)d_in[5];
  float* out = (float*)d_out;

  u16* xb  = (u16*)d_ws;                       // 32 MB bf16 x
  u16* mtb = xb + (size_t)4096 * 4096;         // 32 MB bf16 M^T

  cvt_x<<<dim3(16777216 / (256 * 8)), dim3(256), 0, stream>>>(x, xb);
  build_mt<<<dim3(4096), dim3(256), 0, stream>>>(c0, c1, c2, c3, mtb);
  gemm_bias_relu<<<dim3(16, 16), dim3(512), 0, stream>>>(xb, mtb, b, out);
}